// Round 1
// baseline (887.947 us; speedup 1.0000x reference)
//
#include <hip/hip_runtime.h>
#include <math.h>

#define BATCH 4
#define SEQ 2048
#define FEAT 512
#define NHEADS 8
#define HD 64
#define NROWS (BATCH*SEQ)   // 8192

// C[r, j] = sum_k X[r,k] * W[j,k] + bias[j]
// in_bhtd: gather X from (B,H,T,Hd) layout (k = h*64+hd). out_bhtd: scatter to (B,H,T,Hd).
__global__ __launch_bounds__(256) void proj_kernel(
    const float* __restrict__ X, const float* __restrict__ W,
    const float* __restrict__ bias, float* __restrict__ out,
    const int in_bhtd, const int out_bhtd)
{
  __shared__ float Xs[16][68];   // [k][m], padded
  __shared__ float Ws[16][68];   // [k][n]
  const int tid  = threadIdx.x;
  const int row0 = blockIdx.x << 6;
  const int col0 = blockIdx.y << 6;
  const int ty = tid >> 4, tx = tid & 15;
  const int lr = tid >> 2;          // 0..63
  const int lk = (tid & 3) << 2;    // 0,4,8,12

  float acc[4][4];
#pragma unroll
  for (int i = 0; i < 4; ++i)
#pragma unroll
    for (int j = 0; j < 4; ++j) acc[i][j] = 0.f;

  const int xr = row0 + lr;
  const int wr = col0 + lr;

  for (int k0 = 0; k0 < FEAT; k0 += 16) {
    const int kk = k0 + lk;
    const float* xsrc;
    if (in_bhtd) {
      const int b = xr / SEQ, t = xr - b * SEQ;
      const int h = kk >> 6, hd = kk & 63;
      xsrc = &X[(((size_t)b * NHEADS + h) * SEQ + t) * HD + hd];
    } else {
      xsrc = &X[(size_t)xr * FEAT + kk];
    }
    const float4 xv = *reinterpret_cast<const float4*>(xsrc);
    const float4 wv = *reinterpret_cast<const float4*>(&W[(size_t)wr * FEAT + kk]);
    __syncthreads();   // previous iteration's LDS reads must finish
    Xs[lk+0][lr] = xv.x; Xs[lk+1][lr] = xv.y; Xs[lk+2][lr] = xv.z; Xs[lk+3][lr] = xv.w;
    Ws[lk+0][lr] = wv.x; Ws[lk+1][lr] = wv.y; Ws[lk+2][lr] = wv.z; Ws[lk+3][lr] = wv.w;
    __syncthreads();
#pragma unroll
    for (int k = 0; k < 16; ++k) {
      const float4 av = *reinterpret_cast<const float4*>(&Xs[k][ty << 2]);
      const float4 bv = *reinterpret_cast<const float4*>(&Ws[k][tx << 2]);
      const float ai[4] = {av.x, av.y, av.z, av.w};
      const float bj[4] = {bv.x, bv.y, bv.z, bv.w};
#pragma unroll
      for (int i = 0; i < 4; ++i)
#pragma unroll
        for (int j = 0; j < 4; ++j)
          acc[i][j] = fmaf(ai[i], bj[j], acc[i][j]);
    }
  }

  const int orow = row0 + (ty << 2);
  const int ocol = col0 + (tx << 2);
  const float4 bb = *reinterpret_cast<const float4*>(&bias[ocol]);
  const float bj[4] = {bb.x, bb.y, bb.z, bb.w};
#pragma unroll
  for (int i = 0; i < 4; ++i) {
    const int r = orow + i;
    float4 o;
    o.x = acc[i][0] + bj[0];
    o.y = acc[i][1] + bj[1];
    o.z = acc[i][2] + bj[2];
    o.w = acc[i][3] + bj[3];
    if (out_bhtd) {
      const int b = r / SEQ, t = r - b * SEQ;
      const int h = ocol >> 6, hd = ocol & 63;
      *reinterpret_cast<float4*>(&out[(((size_t)b * NHEADS + h) * SEQ + t) * HD + hd]) = o;
    } else {
      *reinterpret_cast<float4*>(&out[(size_t)r * FEAT + ocol]) = o;
    }
  }
}

// Flash-style attention per (b,h). Q,K,V in (B,H,T,Hd). 64 Q-rows per block.
__global__ __launch_bounds__(256) void attn_kernel(
    const float* __restrict__ Q, const float* __restrict__ K,
    const float* __restrict__ V, float* __restrict__ Oout)
{
  __shared__ float QsT[64][68];  // [hd][r], Q pre-scaled by 1/8
  __shared__ float KsT[64][68];  // [hd][c]; reused as Ps[kk][r] after S-compute
  __shared__ float Vs [64][68];  // [kk][hd]
#define Ps KsT
  const int tid = threadIdx.x;
  const int bh  = blockIdx.y;
  const int q0  = blockIdx.x << 6;
  const int ty = tid >> 4, tx = tid & 15;
  const size_t base = (size_t)bh * SEQ * HD;

  {
    const int lr = tid >> 2;
    const int lh = (tid & 3) << 4;
#pragma unroll
    for (int u = 0; u < 4; ++u) {
      const float4 qv = *reinterpret_cast<const float4*>(
          &Q[base + (size_t)(q0 + lr) * HD + lh + (u << 2)]);
      QsT[lh + (u<<2) + 0][lr] = qv.x * 0.125f;
      QsT[lh + (u<<2) + 1][lr] = qv.y * 0.125f;
      QsT[lh + (u<<2) + 2][lr] = qv.z * 0.125f;
      QsT[lh + (u<<2) + 3][lr] = qv.w * 0.125f;
    }
  }

  float m[4], l[4], o_acc[4][4];
#pragma unroll
  for (int i = 0; i < 4; ++i) {
    m[i] = -INFINITY; l[i] = 0.f;
#pragma unroll
    for (int j = 0; j < 4; ++j) o_acc[i][j] = 0.f;
  }

  for (int kt = 0; kt < SEQ; kt += 64) {
    __syncthreads();   // previous PV reads of KsT/Vs done
    {
      const int lr = tid >> 2;
      const int lh = (tid & 3) << 4;
#pragma unroll
      for (int u = 0; u < 4; ++u) {
        const float4 kv = *reinterpret_cast<const float4*>(
            &K[base + (size_t)(kt + lr) * HD + lh + (u << 2)]);
        KsT[lh + (u<<2) + 0][lr] = kv.x;
        KsT[lh + (u<<2) + 1][lr] = kv.y;
        KsT[lh + (u<<2) + 2][lr] = kv.z;
        KsT[lh + (u<<2) + 3][lr] = kv.w;
        const float4 vv = *reinterpret_cast<const float4*>(
            &V[base + (size_t)(kt + lr) * HD + lh + (u << 2)]);
        *reinterpret_cast<float4*>(&Vs[lr][lh + (u<<2)]) = vv;
      }
    }
    __syncthreads();

    // S = (Q/8) K^T  (64x64 tile; thread owns 4x4)
    float s[4][4];
#pragma unroll
    for (int i = 0; i < 4; ++i)
#pragma unroll
      for (int j = 0; j < 4; ++j) s[i][j] = 0.f;
#pragma unroll 16
    for (int k = 0; k < 64; ++k) {
      const float4 av = *reinterpret_cast<const float4*>(&QsT[k][ty << 2]);
      const float4 bv = *reinterpret_cast<const float4*>(&KsT[k][tx << 2]);
      const float ai[4] = {av.x, av.y, av.z, av.w};
      const float bj[4] = {bv.x, bv.y, bv.z, bv.w};
#pragma unroll
      for (int i = 0; i < 4; ++i)
#pragma unroll
        for (int j = 0; j < 4; ++j)
          s[i][j] = fmaf(ai[i], bj[j], s[i][j]);
    }

    // online softmax
    float p[4][4];
#pragma unroll
    for (int i = 0; i < 4; ++i) {
      float v = fmaxf(fmaxf(s[i][0], s[i][1]), fmaxf(s[i][2], s[i][3]));
      v = fmaxf(v, __shfl_xor(v, 1));
      v = fmaxf(v, __shfl_xor(v, 2));
      v = fmaxf(v, __shfl_xor(v, 4));
      v = fmaxf(v, __shfl_xor(v, 8));
      const float mnew = fmaxf(m[i], v);
      const float corr = __expf(m[i] - mnew);
      float rs = 0.f;
#pragma unroll
      for (int j = 0; j < 4; ++j) { p[i][j] = __expf(s[i][j] - mnew); rs += p[i][j]; }
      rs += __shfl_xor(rs, 1);
      rs += __shfl_xor(rs, 2);
      rs += __shfl_xor(rs, 4);
      rs += __shfl_xor(rs, 8);
      l[i] = l[i] * corr + rs;
      m[i] = mnew;
#pragma unroll
      for (int j = 0; j < 4; ++j) o_acc[i][j] *= corr;
    }

    __syncthreads();   // S-compute reads of KsT done before Ps overwrite
#pragma unroll
    for (int j = 0; j < 4; ++j) {
      float4 pw;
      pw.x = p[0][j]; pw.y = p[1][j]; pw.z = p[2][j]; pw.w = p[3][j];
      *reinterpret_cast<float4*>(&Ps[(tx << 2) + j][ty << 2]) = pw;
    }
    __syncthreads();

    // O += P V
#pragma unroll 16
    for (int k = 0; k < 64; ++k) {
      const float4 pv = *reinterpret_cast<const float4*>(&Ps[k][ty << 2]);
      const float4 vv = *reinterpret_cast<const float4*>(&Vs[k][tx << 2]);
      const float pi[4] = {pv.x, pv.y, pv.z, pv.w};
      const float vj[4] = {vv.x, vv.y, vv.z, vv.w};
#pragma unroll
      for (int i = 0; i < 4; ++i)
#pragma unroll
        for (int j = 0; j < 4; ++j)
          o_acc[i][j] = fmaf(pi[i], vj[j], o_acc[i][j]);
    }
  }

#pragma unroll
  for (int i = 0; i < 4; ++i) {
    const float inv = 1.f / l[i];
    float4 o;
    o.x = o_acc[i][0] * inv;
    o.y = o_acc[i][1] * inv;
    o.z = o_acc[i][2] * inv;
    o.w = o_acc[i][3] * inv;
    const int r = q0 + (ty << 2) + i;
    *reinterpret_cast<float4*>(&Oout[base + (size_t)r * HD + (tx << 2)]) = o;
  }
#undef Ps
}

extern "C" void kernel_launch(void* const* d_in, const int* in_sizes, int n_in,
                              void* d_out, int out_size, void* d_ws, size_t ws_size,
                              hipStream_t stream) {
  const float* x_cur  = (const float*)d_in[0];
  const float* x_past = (const float*)d_in[1];
  const float* wq = (const float*)d_in[2];
  const float* bq = (const float*)d_in[3];
  const float* wk = (const float*)d_in[4];
  const float* bk = (const float*)d_in[5];
  const float* wv = (const float*)d_in[6];
  const float* bv = (const float*)d_in[7];
  const float* wo = (const float*)d_in[8];
  const float* bo = (const float*)d_in[9];
  float* out = (float*)d_out;

  const size_t n = (size_t)NROWS * FEAT;   // 4,194,304 floats
  float* Qb = (float*)d_ws;
  float* Kb = Qb + n;
  float* Vb = Kb + n;
  float* AO = Vb + n;

  dim3 block(256);
  dim3 gproj(NROWS / 64, FEAT / 64);
  proj_kernel<<<gproj, block, 0, stream>>>(x_cur,  wq, bq, Qb, 0, 1);
  proj_kernel<<<gproj, block, 0, stream>>>(x_past, wk, bk, Kb, 0, 1);
  proj_kernel<<<gproj, block, 0, stream>>>(x_past, wv, bv, Vb, 0, 1);

  dim3 gattn(SEQ / 64, BATCH * NHEADS);
  attn_kernel<<<gattn, block, 0, stream>>>(Qb, Kb, Vb, AO);

  proj_kernel<<<gproj, block, 0, stream>>>(AO, wo, bo, out, 1, 0);
}

// Round 2
// 339.967 us; speedup vs baseline: 2.6119x; 2.6119x over previous
//
#include <hip/hip_runtime.h>
#include <math.h>

#define BATCH 4
#define SEQ 2048
#define FEAT 512
#define NHEADS 8
#define HD 64
#define NROWS (BATCH*SEQ)   // 8192

typedef __attribute__((ext_vector_type(4))) float f32x4;
typedef __attribute__((ext_vector_type(8))) short s16x8;
typedef __attribute__((ext_vector_type(4))) unsigned short u16x4;

static __device__ __forceinline__ unsigned short f2bf(float x) {
  unsigned int u = __builtin_bit_cast(unsigned int, x);
  unsigned int r = (u + 0x7FFFu + ((u >> 16) & 1u)) >> 16;
  return (unsigned short)r;
}
static __device__ __forceinline__ float bf2f(unsigned short h) {
  unsigned int u = ((unsigned int)h) << 16;
  return __builtin_bit_cast(float, u);
}
static __device__ __forceinline__ void split2(float x, unsigned short& h, unsigned short& l) {
  h = f2bf(x);
  l = f2bf(x - bf2f(h));
}

// ---------------------------------------------------------------------------
// Split-bf16 MFMA GEMM: C[r,j] = sum_k X[r,k]*W[j,k] + bias[j]
// BM=128, BN=64, BK=64. 4 waves: wave grid 2x2, wave tile 64x32.
// out_bhtd: scatter output rows (B,T) x cols (H,Hd) -> (B,H,T,Hd)
// ---------------------------------------------------------------------------
__global__ __launch_bounds__(256) void proj_mfma(
    const float* __restrict__ X, const float* __restrict__ W,
    const float* __restrict__ bias, float* __restrict__ out,
    const int out_bhtd)
{
  __shared__ unsigned short Xhi[128 * 64], Xlo[128 * 64];
  __shared__ unsigned short Whi[64 * 64],  Wlo[64 * 64];

  const int tid  = threadIdx.x;
  const int lane = tid & 63;
  const int wave = tid >> 6;
  const int wm = (wave >> 1) * 64;   // wave row offset in tile
  const int wn = (wave & 1) * 32;    // wave col offset in tile
  const int row0 = blockIdx.x * 128;
  const int col0 = blockIdx.y * 64;

  f32x4 acc[4][2];
#pragma unroll
  for (int mi = 0; mi < 4; ++mi)
#pragma unroll
    for (int ni = 0; ni < 2; ++ni) acc[mi][ni] = (f32x4)0.f;

  const int srow = tid >> 4;        // 0..15
  const int sk   = (tid & 15) * 4;  // 0..60

  for (int kt = 0; kt < FEAT; kt += 64) {
    // load staging data to registers first (overlap with barrier)
    f32x4 xr[8], wr[4];
#pragma unroll
    for (int p = 0; p < 8; ++p) {
      const int r = srow + p * 16;
      xr[p] = *reinterpret_cast<const f32x4*>(&X[(size_t)(row0 + r) * FEAT + kt + sk]);
    }
#pragma unroll
    for (int p = 0; p < 4; ++p) {
      const int r = srow + p * 16;
      wr[p] = *reinterpret_cast<const f32x4*>(&W[(size_t)(col0 + r) * FEAT + kt + sk]);
    }
    __syncthreads();  // all waves done reading previous tile
#pragma unroll
    for (int p = 0; p < 8; ++p) {
      const int r = srow + p * 16;
      const int el = r * 64 + (sk ^ ((r & 7) << 3));
      u16x4 h, l;
#pragma unroll
      for (int i = 0; i < 4; ++i) { unsigned short hh, ll; split2(xr[p][i], hh, ll); h[i] = hh; l[i] = ll; }
      *reinterpret_cast<u16x4*>(&Xhi[el]) = h;
      *reinterpret_cast<u16x4*>(&Xlo[el]) = l;
    }
#pragma unroll
    for (int p = 0; p < 4; ++p) {
      const int r = srow + p * 16;
      const int el = r * 64 + (sk ^ ((r & 7) << 3));
      u16x4 h, l;
#pragma unroll
      for (int i = 0; i < 4; ++i) { unsigned short hh, ll; split2(wr[p][i], hh, ll); h[i] = hh; l[i] = ll; }
      *reinterpret_cast<u16x4*>(&Whi[el]) = h;
      *reinterpret_cast<u16x4*>(&Wlo[el]) = l;
    }
    __syncthreads();

#pragma unroll
    for (int c = 0; c < 2; ++c) {
      const int koff = c * 32 + (lane >> 4) * 8;
      s16x8 ah[4], al[4], bh[2], bl[2];
#pragma unroll
      for (int mi = 0; mi < 4; ++mi) {
        const int r = wm + mi * 16 + (lane & 15);
        const int el = r * 64 + (koff ^ ((r & 7) << 3));
        ah[mi] = *reinterpret_cast<const s16x8*>(&Xhi[el]);
        al[mi] = *reinterpret_cast<const s16x8*>(&Xlo[el]);
      }
#pragma unroll
      for (int ni = 0; ni < 2; ++ni) {
        const int r = wn + ni * 16 + (lane & 15);
        const int el = r * 64 + (koff ^ ((r & 7) << 3));
        bh[ni] = *reinterpret_cast<const s16x8*>(&Whi[el]);
        bl[ni] = *reinterpret_cast<const s16x8*>(&Wlo[el]);
      }
#pragma unroll
      for (int mi = 0; mi < 4; ++mi)
#pragma unroll
        for (int ni = 0; ni < 2; ++ni) {
          acc[mi][ni] = __builtin_amdgcn_mfma_f32_16x16x32_bf16(ah[mi], bh[ni], acc[mi][ni], 0, 0, 0);
          acc[mi][ni] = __builtin_amdgcn_mfma_f32_16x16x32_bf16(ah[mi], bl[ni], acc[mi][ni], 0, 0, 0);
          acc[mi][ni] = __builtin_amdgcn_mfma_f32_16x16x32_bf16(al[mi], bh[ni], acc[mi][ni], 0, 0, 0);
        }
    }
  }

  // epilogue: bias + store (C layout: col = lane&15, row = (lane>>4)*4 + reg)
#pragma unroll
  for (int ni = 0; ni < 2; ++ni) {
    const int colc = col0 + wn + ni * 16 + (lane & 15);
    const float bj = bias[colc];
#pragma unroll
    for (int mi = 0; mi < 4; ++mi) {
#pragma unroll
      for (int r = 0; r < 4; ++r) {
        const int rowc = row0 + wm + mi * 16 + ((lane >> 4) << 2) + r;
        const float v = acc[mi][ni][r] + bj;
        if (out_bhtd) {
          const int b = rowc >> 11, t = rowc & 2047;
          const int h = colc >> 6, hd = colc & 63;
          out[(((size_t)b * NHEADS + h) * SEQ + t) * HD + hd] = v;
        } else {
          out[(size_t)rowc * FEAT + colc] = v;
        }
      }
    }
  }
}

// ---------------------------------------------------------------------------
// Flash attention, split-bf16 MFMA. One block = one (b,h) x 64 Q rows.
// 4 waves, each owns 16 Q rows. K-tiles of 64 keys.
// ---------------------------------------------------------------------------
__global__ __launch_bounds__(256) void attn_mfma(
    const float* __restrict__ Q, const float* __restrict__ K,
    const float* __restrict__ V, float* __restrict__ Oout)
{
  __shared__ unsigned short Khi[64 * 64], Klo[64 * 64];
  __shared__ unsigned short Vthi[64 * 64], Vtlo[64 * 64];   // transposed: [hd][key]
  __shared__ unsigned short Phi[4][16 * 64], Plo[4][16 * 64]; // per-wave private

  const int tid = threadIdx.x, lane = tid & 63, wave = tid >> 6;
  const int bh = blockIdx.y;
  const int q0 = blockIdx.x * 64;
  const size_t base = (size_t)bh * SEQ * HD;
  const int b = bh >> 3, h = bh & 7;

  // Q fragments (A-operand), scaled by 1/sqrt(Hd)=1/8, split hi/lo. 2 k-chunks.
  s16x8 qhi[2], qlo[2];
  {
    const int qrow = q0 + wave * 16 + (lane & 15);
#pragma unroll
    for (int c = 0; c < 2; ++c) {
      const int hd0 = c * 32 + (lane >> 4) * 8;
      const f32x4 a0 = *reinterpret_cast<const f32x4*>(&Q[base + (size_t)qrow * HD + hd0]);
      const f32x4 a1 = *reinterpret_cast<const f32x4*>(&Q[base + (size_t)qrow * HD + hd0 + 4]);
#pragma unroll
      for (int j = 0; j < 8; ++j) {
        const float v = (j < 4 ? a0[j] : a1[j - 4]) * 0.125f;
        unsigned short hh, ll; split2(v, hh, ll);
        qhi[c][j] = (short)hh; qlo[c][j] = (short)ll;
      }
    }
  }

  f32x4 oacc[4];
  float m[4], l[4];
#pragma unroll
  for (int n = 0; n < 4; ++n) oacc[n] = (f32x4)0.f;
#pragma unroll
  for (int r = 0; r < 4; ++r) { m[r] = -INFINITY; l[r] = 0.f; }

  const int skey = tid >> 2;        // 0..63
  const int shq  = (tid & 3) << 4;  // 0,16,32,48

  for (int kt = 0; kt < SEQ; kt += 64) {
    // ---- stage K, V(transposed) hi/lo into LDS ----
    f32x4 kv[4], vv[4];
#pragma unroll
    for (int u = 0; u < 4; ++u) {
      kv[u] = *reinterpret_cast<const f32x4*>(&K[base + (size_t)(kt + skey) * HD + shq + u * 4]);
      vv[u] = *reinterpret_cast<const f32x4*>(&V[base + (size_t)(kt + skey) * HD + shq + u * 4]);
    }
    __syncthreads();  // previous iteration's K/Vt reads complete
#pragma unroll
    for (int u = 0; u < 4; ++u) {
      const int hd = shq + u * 4;
      u16x4 h4, l4;
#pragma unroll
      for (int i = 0; i < 4; ++i) { unsigned short hh, ll; split2(kv[u][i], hh, ll); h4[i] = hh; l4[i] = ll; }
      const int el = skey * 64 + (hd ^ ((skey & 7) << 3));
      *reinterpret_cast<u16x4*>(&Khi[el]) = h4;
      *reinterpret_cast<u16x4*>(&Klo[el]) = l4;
#pragma unroll
      for (int i = 0; i < 4; ++i) {
        unsigned short vh, vl; split2(vv[u][i], vh, vl);
        const int hdi = hd + i;
        const int elv = hdi * 64 + (skey ^ ((hdi & 7) << 3));
        Vthi[elv] = vh; Vtlo[elv] = vl;
      }
    }
    __syncthreads();

    // ---- S = (Q/8) K^T : 4 n-tiles of 16 keys, k = Hd in 2 chunks ----
    f32x4 s[4];
#pragma unroll
    for (int n = 0; n < 4; ++n) s[n] = (f32x4)0.f;
#pragma unroll
    for (int c = 0; c < 2; ++c) {
      const int koff = c * 32 + (lane >> 4) * 8;
#pragma unroll
      for (int n = 0; n < 4; ++n) {
        const int key = n * 16 + (lane & 15);
        const int el = key * 64 + (koff ^ ((key & 7) << 3));
        const s16x8 kh = *reinterpret_cast<const s16x8*>(&Khi[el]);
        const s16x8 kl = *reinterpret_cast<const s16x8*>(&Klo[el]);
        s[n] = __builtin_amdgcn_mfma_f32_16x16x32_bf16(qhi[c], kh, s[n], 0, 0, 0);
        s[n] = __builtin_amdgcn_mfma_f32_16x16x32_bf16(qhi[c], kl, s[n], 0, 0, 0);
        s[n] = __builtin_amdgcn_mfma_f32_16x16x32_bf16(qlo[c], kh, s[n], 0, 0, 0);
      }
    }

    // ---- online softmax (rows live in 16-lane groups; reg r = row) ----
#pragma unroll
    for (int r = 0; r < 4; ++r) {
      float mx = fmaxf(fmaxf(s[0][r], s[1][r]), fmaxf(s[2][r], s[3][r]));
      mx = fmaxf(mx, __shfl_xor(mx, 1));
      mx = fmaxf(mx, __shfl_xor(mx, 2));
      mx = fmaxf(mx, __shfl_xor(mx, 4));
      mx = fmaxf(mx, __shfl_xor(mx, 8));
      const float mnew = fmaxf(m[r], mx);
      const float corr = __expf(m[r] - mnew);
      float rs = 0.f;
#pragma unroll
      for (int n = 0; n < 4; ++n) { const float p = __expf(s[n][r] - mnew); s[n][r] = p; rs += p; }
      rs += __shfl_xor(rs, 1);
      rs += __shfl_xor(rs, 2);
      rs += __shfl_xor(rs, 4);
      rs += __shfl_xor(rs, 8);
      l[r] = l[r] * corr + rs; m[r] = mnew;
#pragma unroll
      for (int n = 0; n < 4; ++n) oacc[n][r] *= corr;
    }

    // ---- write P (hi/lo) to per-wave LDS region ----
    unsigned short* ph = Phi[wave];
    unsigned short* pl = Plo[wave];
#pragma unroll
    for (int r = 0; r < 4; ++r) {
      const int prow = ((lane >> 4) << 2) + r;
      const int rowoff = prow * 64;
      const int sw = (prow & 7) << 3;
#pragma unroll
      for (int n = 0; n < 4; ++n) {
        const int col = n * 16 + (lane & 15);
        const int el = rowoff + (col ^ sw);
        unsigned short hh, ll; split2(s[n][r], hh, ll);
        ph[el] = hh; pl[el] = ll;
      }
    }

    // ---- O += P V ----
    s16x8 pah[2], pal[2];
#pragma unroll
    for (int c = 0; c < 2; ++c) {
      const int prow = lane & 15;
      const int key0 = c * 32 + (lane >> 4) * 8;
      const int el = prow * 64 + (key0 ^ ((prow & 7) << 3));
      pah[c] = *reinterpret_cast<const s16x8*>(&ph[el]);
      pal[c] = *reinterpret_cast<const s16x8*>(&pl[el]);
    }
#pragma unroll
    for (int c = 0; c < 2; ++c) {
      const int key0 = c * 32 + (lane >> 4) * 8;
#pragma unroll
      for (int n = 0; n < 4; ++n) {
        const int hd = n * 16 + (lane & 15);
        const int el = hd * 64 + (key0 ^ ((hd & 7) << 3));
        const s16x8 vh = *reinterpret_cast<const s16x8*>(&Vthi[el]);
        const s16x8 vl = *reinterpret_cast<const s16x8*>(&Vtlo[el]);
        oacc[n] = __builtin_amdgcn_mfma_f32_16x16x32_bf16(pah[c], vh, oacc[n], 0, 0, 0);
        oacc[n] = __builtin_amdgcn_mfma_f32_16x16x32_bf16(pah[c], vl, oacc[n], 0, 0, 0);
        oacc[n] = __builtin_amdgcn_mfma_f32_16x16x32_bf16(pal[c], vh, oacc[n], 0, 0, 0);
      }
    }
  }

  // ---- normalize + store to (B,T,D) layout ----
  float inv[4];
#pragma unroll
  for (int r = 0; r < 4; ++r) inv[r] = 1.f / l[r];
#pragma unroll
  for (int n = 0; n < 4; ++n) {
    const int hd = n * 16 + (lane & 15);
#pragma unroll
    for (int r = 0; r < 4; ++r) {
      const int q = q0 + wave * 16 + ((lane >> 4) << 2) + r;
      Oout[((size_t)b * SEQ + q) * FEAT + h * HD + hd] = oacc[n][r] * inv[r];
    }
  }
}

extern "C" void kernel_launch(void* const* d_in, const int* in_sizes, int n_in,
                              void* d_out, int out_size, void* d_ws, size_t ws_size,
                              hipStream_t stream) {
  const float* x_cur  = (const float*)d_in[0];
  const float* x_past = (const float*)d_in[1];
  const float* wq = (const float*)d_in[2];
  const float* bq = (const float*)d_in[3];
  const float* wk = (const float*)d_in[4];
  const float* bk = (const float*)d_in[5];
  const float* wv = (const float*)d_in[6];
  const float* bv = (const float*)d_in[7];
  const float* wo = (const float*)d_in[8];
  const float* bo = (const float*)d_in[9];
  float* out = (float*)d_out;

  const size_t n = (size_t)NROWS * FEAT;
  float* Qb = (float*)d_ws;        // (B,H,T,Hd)
  float* Kb = Qb + n;              // (B,H,T,Hd)
  float* Vb = Kb + n;              // (B,H,T,Hd)
  float* AO = Vb + n;              // (B,T,D)

  dim3 block(256);
  dim3 gproj(NROWS / 128, FEAT / 64);
  proj_mfma<<<gproj, block, 0, stream>>>(x_cur,  wq, bq, Qb, 1);
  proj_mfma<<<gproj, block, 0, stream>>>(x_past, wk, bk, Kb, 1);
  proj_mfma<<<gproj, block, 0, stream>>>(x_past, wv, bv, Vb, 1);

  dim3 gattn(SEQ / 64, BATCH * NHEADS);
  attn_mfma<<<gattn, block, 0, stream>>>(Qb, Kb, Vb, AO);

  proj_mfma<<<gproj, block, 0, stream>>>(AO, wo, bo, out, 0);
}

// Round 3
// 268.138 us; speedup vs baseline: 3.3115x; 1.2679x over previous
//
#include <hip/hip_runtime.h>
#include <math.h>

#define BATCH 4
#define SEQ 2048
#define FEAT 512
#define NHEADS 8
#define HD 64
#define NROWS (BATCH*SEQ)   // 8192

typedef __attribute__((ext_vector_type(4))) float f32x4;
typedef __attribute__((ext_vector_type(8))) short s16x8;
typedef __attribute__((ext_vector_type(8))) unsigned short u16x8;

static __device__ __forceinline__ unsigned short f2bf(float x) {
  unsigned int u = __builtin_bit_cast(unsigned int, x);
  unsigned int r = (u + 0x7FFFu + ((u >> 16) & 1u)) >> 16;
  return (unsigned short)r;
}
static __device__ __forceinline__ float bf2f(unsigned short h) {
  unsigned int u = ((unsigned int)h) << 16;
  return __builtin_bit_cast(float, u);
}
static __device__ __forceinline__ void split2(float x, unsigned short& h, unsigned short& l) {
  h = f2bf(x);
  l = f2bf(x - bf2f(h));
}

// ---------------------------------------------------------------------------
// Fused QKV projection. z=0: Q (scale 1/8) -> (B,H,T,Hd) hi/lo
//                       z=1: K            -> (B,H,T,Hd) hi/lo
//                       z=2: V            -> (B,H,Hd,T) hi/lo (LDS transpose)
// BM=128, BN=64, BK=64; 4 waves (2x2), wave tile 64x32.
// ---------------------------------------------------------------------------
__global__ __launch_bounds__(256) void qkv_proj(
    const float* __restrict__ xc, const float* __restrict__ xp,
    const float* __restrict__ wq, const float* __restrict__ bq,
    const float* __restrict__ wk, const float* __restrict__ bk,
    const float* __restrict__ wv, const float* __restrict__ bv,
    unsigned short* __restrict__ Qhi, unsigned short* __restrict__ Qlo,
    unsigned short* __restrict__ Khi, unsigned short* __restrict__ Klo,
    unsigned short* __restrict__ Vthi, unsigned short* __restrict__ Vtlo)
{
  __shared__ unsigned short Xhi[128 * 64], Xlo[128 * 64];
  __shared__ unsigned short Whi[64 * 64],  Wlo[64 * 64];

  const int z = blockIdx.z;
  const float* X  = (z == 0) ? xc : xp;
  const float* W  = (z == 0) ? wq : (z == 1) ? wk : wv;
  const float* Bp = (z == 0) ? bq : (z == 1) ? bk : bv;
  unsigned short* Ohi = (z == 0) ? Qhi : (z == 1) ? Khi : Vthi;
  unsigned short* Olo = (z == 0) ? Qlo : (z == 1) ? Klo : Vtlo;
  const float scale = (z == 0) ? 0.125f : 1.0f;

  const int tid  = threadIdx.x;
  const int lane = tid & 63;
  const int wave = tid >> 6;
  const int g = lane >> 4, j = lane & 15;
  const int wm = (wave >> 1) * 64;
  const int wn = (wave & 1) * 32;
  const int row0 = blockIdx.x * 128;
  const int col0 = blockIdx.y * 64;

  f32x4 acc[4][2];
#pragma unroll
  for (int mi = 0; mi < 4; ++mi)
#pragma unroll
    for (int ni = 0; ni < 2; ++ni) acc[mi][ni] = (f32x4)0.f;

  const int srow = tid >> 4;        // 0..15
  const int sk   = (tid & 15) * 4;  // 0..60

  for (int kt = 0; kt < FEAT; kt += 64) {
    f32x4 xr[8], wr[4];
#pragma unroll
    for (int p = 0; p < 8; ++p)
      xr[p] = *reinterpret_cast<const f32x4*>(&X[(size_t)(row0 + srow + p * 16) * FEAT + kt + sk]);
#pragma unroll
    for (int p = 0; p < 4; ++p)
      wr[p] = *reinterpret_cast<const f32x4*>(&W[(size_t)(col0 + srow + p * 16) * FEAT + kt + sk]);
    __syncthreads();
#pragma unroll
    for (int p = 0; p < 8; ++p) {
      const int r = srow + p * 16;
      const int el = r * 64 + (sk ^ ((r & 7) << 3));
#pragma unroll
      for (int i = 0; i < 4; ++i) { unsigned short hh, ll; split2(xr[p][i], hh, ll); Xhi[el + i] = hh; Xlo[el + i] = ll; }
    }
#pragma unroll
    for (int p = 0; p < 4; ++p) {
      const int r = srow + p * 16;
      const int el = r * 64 + (sk ^ ((r & 7) << 3));
#pragma unroll
      for (int i = 0; i < 4; ++i) { unsigned short hh, ll; split2(wr[p][i], hh, ll); Whi[el + i] = hh; Wlo[el + i] = ll; }
    }
    __syncthreads();

#pragma unroll
    for (int c = 0; c < 2; ++c) {
      const int koff = c * 32 + g * 8;
      s16x8 ah[4], al[4], bh[2], bl[2];
#pragma unroll
      for (int mi = 0; mi < 4; ++mi) {
        const int r = wm + mi * 16 + j;
        const int el = r * 64 + (koff ^ ((r & 7) << 3));
        ah[mi] = *reinterpret_cast<const s16x8*>(&Xhi[el]);
        al[mi] = *reinterpret_cast<const s16x8*>(&Xlo[el]);
      }
#pragma unroll
      for (int ni = 0; ni < 2; ++ni) {
        const int r = wn + ni * 16 + j;
        const int el = r * 64 + (koff ^ ((r & 7) << 3));
        bh[ni] = *reinterpret_cast<const s16x8*>(&Whi[el]);
        bl[ni] = *reinterpret_cast<const s16x8*>(&Wlo[el]);
      }
#pragma unroll
      for (int mi = 0; mi < 4; ++mi)
#pragma unroll
        for (int ni = 0; ni < 2; ++ni) {
          acc[mi][ni] = __builtin_amdgcn_mfma_f32_16x16x32_bf16(ah[mi], bh[ni], acc[mi][ni], 0, 0, 0);
          acc[mi][ni] = __builtin_amdgcn_mfma_f32_16x16x32_bf16(ah[mi], bl[ni], acc[mi][ni], 0, 0, 0);
          acc[mi][ni] = __builtin_amdgcn_mfma_f32_16x16x32_bf16(al[mi], bh[ni], acc[mi][ni], 0, 0, 0);
        }
    }
  }

  if (z < 2) {
    // split store to (B,H,T,Hd)
#pragma unroll
    for (int ni = 0; ni < 2; ++ni) {
      const int colc = col0 + wn + ni * 16 + j;
      const float bj = Bp[colc];
      const int h = colc >> 6, hd = colc & 63;
#pragma unroll
      for (int mi = 0; mi < 4; ++mi)
#pragma unroll
        for (int r = 0; r < 4; ++r) {
          const int rowc = row0 + wm + mi * 16 + (g << 2) + r;
          const int b = rowc >> 11, t = rowc & 2047;
          const float v = (acc[mi][ni][r] + bj) * scale;
          unsigned short hh, ll; split2(v, hh, ll);
          const size_t off = (((size_t)b * NHEADS + h) * SEQ + t) * HD + hd;
          Ohi[off] = hh; Olo[off] = ll;
        }
    }
  } else {
    // V: transpose via LDS -> (B,H,Hd,T)
    __syncthreads();   // main-loop reads of Xhi/Xlo done
#pragma unroll
    for (int ni = 0; ni < 2; ++ni) {
      const int hdl = wn + ni * 16 + j;          // 0..63 local col (hd)
      const float bj = Bp[col0 + hdl];
#pragma unroll
      for (int mi = 0; mi < 4; ++mi)
#pragma unroll
        for (int r = 0; r < 4; ++r) {
          const int lt = wm + mi * 16 + (g << 2) + r;   // 0..127 local t
          const float v = acc[mi][ni][r] + bj;
          unsigned short hh, ll; split2(v, hh, ll);
          const int el = lt * 64 + (hdl ^ ((lt & 7) << 3));
          Xhi[el] = hh; Xlo[el] = ll;
        }
    }
    __syncthreads();
    const int b = row0 >> 11, h = col0 >> 6;
    const int tbase = row0 & 2047;
#pragma unroll
    for (int c = 0; c < 4; ++c) {
      const int chunk = c * 256 + tid;     // 0..1023
      const int hd = chunk >> 4;           // 0..63
      const int t0 = (chunk & 15) * 8;     // 0..120
      u16x8 vh, vl;
#pragma unroll
      for (int i = 0; i < 8; ++i) {
        const int lt = t0 + i;
        const int el = lt * 64 + (hd ^ ((lt & 7) << 3));
        vh[i] = Xhi[el]; vl[i] = Xlo[el];
      }
      const size_t off = (((size_t)b * NHEADS + h) * HD + hd) * SEQ + tbase + t0;
      *reinterpret_cast<u16x8*>(&Vthi[off]) = vh;
      *reinterpret_cast<u16x8*>(&Vtlo[off]) = vl;
    }
  }
}

// ---------------------------------------------------------------------------
// Output projection: out[r,j] = sum_k AO[r,k]*wo[j,k] + bo[j], fp32 out (B,T,D)
// ---------------------------------------------------------------------------
__global__ __launch_bounds__(256) void out_proj(
    const float* __restrict__ X, const float* __restrict__ W,
    const float* __restrict__ bias, float* __restrict__ out)
{
  __shared__ unsigned short Xhi[128 * 64], Xlo[128 * 64];
  __shared__ unsigned short Whi[64 * 64],  Wlo[64 * 64];

  const int tid  = threadIdx.x;
  const int lane = tid & 63;
  const int wave = tid >> 6;
  const int g = lane >> 4, j = lane & 15;
  const int wm = (wave >> 1) * 64;
  const int wn = (wave & 1) * 32;
  const int row0 = blockIdx.x * 128;
  const int col0 = blockIdx.y * 64;

  f32x4 acc[4][2];
#pragma unroll
  for (int mi = 0; mi < 4; ++mi)
#pragma unroll
    for (int ni = 0; ni < 2; ++ni) acc[mi][ni] = (f32x4)0.f;

  const int srow = tid >> 4;
  const int sk   = (tid & 15) * 4;

  for (int kt = 0; kt < FEAT; kt += 64) {
    f32x4 xr[8], wr[4];
#pragma unroll
    for (int p = 0; p < 8; ++p)
      xr[p] = *reinterpret_cast<const f32x4*>(&X[(size_t)(row0 + srow + p * 16) * FEAT + kt + sk]);
#pragma unroll
    for (int p = 0; p < 4; ++p)
      wr[p] = *reinterpret_cast<const f32x4*>(&W[(size_t)(col0 + srow + p * 16) * FEAT + kt + sk]);
    __syncthreads();
#pragma unroll
    for (int p = 0; p < 8; ++p) {
      const int r = srow + p * 16;
      const int el = r * 64 + (sk ^ ((r & 7) << 3));
#pragma unroll
      for (int i = 0; i < 4; ++i) { unsigned short hh, ll; split2(xr[p][i], hh, ll); Xhi[el + i] = hh; Xlo[el + i] = ll; }
    }
#pragma unroll
    for (int p = 0; p < 4; ++p) {
      const int r = srow + p * 16;
      const int el = r * 64 + (sk ^ ((r & 7) << 3));
#pragma unroll
      for (int i = 0; i < 4; ++i) { unsigned short hh, ll; split2(wr[p][i], hh, ll); Whi[el + i] = hh; Wlo[el + i] = ll; }
    }
    __syncthreads();

#pragma unroll
    for (int c = 0; c < 2; ++c) {
      const int koff = c * 32 + g * 8;
      s16x8 ah[4], al[4], bh[2], bl[2];
#pragma unroll
      for (int mi = 0; mi < 4; ++mi) {
        const int r = wm + mi * 16 + j;
        const int el = r * 64 + (koff ^ ((r & 7) << 3));
        ah[mi] = *reinterpret_cast<const s16x8*>(&Xhi[el]);
        al[mi] = *reinterpret_cast<const s16x8*>(&Xlo[el]);
      }
#pragma unroll
      for (int ni = 0; ni < 2; ++ni) {
        const int r = wn + ni * 16 + j;
        const int el = r * 64 + (koff ^ ((r & 7) << 3));
        bh[ni] = *reinterpret_cast<const s16x8*>(&Whi[el]);
        bl[ni] = *reinterpret_cast<const s16x8*>(&Wlo[el]);
      }
#pragma unroll
      for (int mi = 0; mi < 4; ++mi)
#pragma unroll
        for (int ni = 0; ni < 2; ++ni) {
          acc[mi][ni] = __builtin_amdgcn_mfma_f32_16x16x32_bf16(ah[mi], bh[ni], acc[mi][ni], 0, 0, 0);
          acc[mi][ni] = __builtin_amdgcn_mfma_f32_16x16x32_bf16(ah[mi], bl[ni], acc[mi][ni], 0, 0, 0);
          acc[mi][ni] = __builtin_amdgcn_mfma_f32_16x16x32_bf16(al[mi], bh[ni], acc[mi][ni], 0, 0, 0);
        }
    }
  }

#pragma unroll
  for (int ni = 0; ni < 2; ++ni) {
    const int colc = col0 + wn + ni * 16 + j;
    const float bj = bias[colc];
#pragma unroll
    for (int mi = 0; mi < 4; ++mi)
#pragma unroll
      for (int r = 0; r < 4; ++r) {
        const int rowc = row0 + wm + mi * 16 + (g << 2) + r;
        out[(size_t)rowc * FEAT + colc] = acc[mi][ni][r] + bj;
      }
  }
}

// ---------------------------------------------------------------------------
// Flash attention, split-bf16 MFMA, pre-split inputs.
// Block: 4 waves x 16 Q-rows = 64 Q-rows; K-tiles of 64 keys, prefetched.
// ---------------------------------------------------------------------------
__global__ __launch_bounds__(256, 3) void attn_mfma(
    const unsigned short* __restrict__ Qhi, const unsigned short* __restrict__ Qlo,
    const unsigned short* __restrict__ Khi, const unsigned short* __restrict__ Klo,
    const unsigned short* __restrict__ Vthi, const unsigned short* __restrict__ Vtlo,
    float* __restrict__ AO)
{
  __shared__ unsigned short Ksh_hi[64 * 64], Ksh_lo[64 * 64];
  __shared__ unsigned short Vsh_hi[64 * 64], Vsh_lo[64 * 64];
  __shared__ unsigned int   Pw[4][16 * 68];   // packed hi|lo<<16, row stride 68

  const int tid = threadIdx.x, lane = tid & 63, wave = tid >> 6;
  const int g = lane >> 4, j = lane & 15;
  const int bh = blockIdx.y;
  const int q0 = blockIdx.x * 64;
  const size_t base = (size_t)bh * SEQ * HD;
  const int b = bh >> 3, h = bh & 7;

  // Q fragments (pre-scaled by 1/8 in proj)
  s16x8 qh[2], ql[2];
  {
    const int qrow = q0 + wave * 16 + j;
#pragma unroll
    for (int c = 0; c < 2; ++c) {
      const size_t off = base + (size_t)qrow * HD + c * 32 + g * 8;
      qh[c] = *reinterpret_cast<const s16x8*>(&Qhi[off]);
      ql[c] = *reinterpret_cast<const s16x8*>(&Qlo[off]);
    }
  }

  f32x4 oacc[4];
  float m[4], l[4];
#pragma unroll
  for (int n = 0; n < 4; ++n) oacc[n] = (f32x4)0.f;
#pragma unroll
  for (int r = 0; r < 4; ++r) { m[r] = -INFINITY; l[r] = 0.f; }

  // staging: 8 chunks of 16B per thread: c>>1 selects {Khi,Klo,Vthi,Vtlo}
  const int srow = (tid >> 3) & 31;        // row within half-array handled below
  const int st0  = (tid & 7) * 8;
  u16x8 stg[8];

#define LOAD_TILE(KT)                                                          \
  {                                                                            \
    _Pragma("unroll")                                                          \
    for (int c = 0; c < 8; ++c) {                                              \
      const int row = (c & 1) * 32 + srow;                                     \
      const unsigned short* src;                                               \
      if ((c >> 1) == 0)      src = &Khi [base + (size_t)((KT) + row) * HD + st0]; \
      else if ((c >> 1) == 1) src = &Klo [base + (size_t)((KT) + row) * HD + st0]; \
      else if ((c >> 1) == 2) src = &Vthi[base + (size_t)row * SEQ + (KT) + st0];  \
      else                    src = &Vtlo[base + (size_t)row * SEQ + (KT) + st0];  \
      stg[c] = *reinterpret_cast<const u16x8*>(src);                           \
    }                                                                          \
  }

  LOAD_TILE(0)

  for (int kt = 0; kt < SEQ; kt += 64) {
    __syncthreads();   // previous tile's LDS reads complete
#pragma unroll
    for (int c = 0; c < 8; ++c) {
      const int row = (c & 1) * 32 + srow;
      const int el = row * 64 + (st0 ^ ((row & 7) << 3));
      unsigned short* dst = ((c >> 1) == 0) ? Ksh_hi : ((c >> 1) == 1) ? Ksh_lo
                          : ((c >> 1) == 2) ? Vsh_hi : Vsh_lo;
      *reinterpret_cast<u16x8*>(&dst[el]) = stg[c];
    }
    __syncthreads();
    if (kt + 64 < SEQ) LOAD_TILE(kt + 64)   // prefetch next tile

    // ---- S = (Q/8) K^T ----
    f32x4 s[4];
#pragma unroll
    for (int n = 0; n < 4; ++n) s[n] = (f32x4)0.f;
#pragma unroll
    for (int c = 0; c < 2; ++c) {
      const int koff = c * 32 + g * 8;
#pragma unroll
      for (int n = 0; n < 4; ++n) {
        const int key = n * 16 + j;
        const int el = key * 64 + (koff ^ ((key & 7) << 3));
        const s16x8 kh = *reinterpret_cast<const s16x8*>(&Ksh_hi[el]);
        const s16x8 kl = *reinterpret_cast<const s16x8*>(&Ksh_lo[el]);
        s[n] = __builtin_amdgcn_mfma_f32_16x16x32_bf16(qh[c], kh, s[n], 0, 0, 0);
        s[n] = __builtin_amdgcn_mfma_f32_16x16x32_bf16(qh[c], kl, s[n], 0, 0, 0);
        s[n] = __builtin_amdgcn_mfma_f32_16x16x32_bf16(ql[c], kh, s[n], 0, 0, 0);
      }
    }

    // ---- online softmax ----
#pragma unroll
    for (int r = 0; r < 4; ++r) {
      float mx = fmaxf(fmaxf(s[0][r], s[1][r]), fmaxf(s[2][r], s[3][r]));
      mx = fmaxf(mx, __shfl_xor(mx, 1));
      mx = fmaxf(mx, __shfl_xor(mx, 2));
      mx = fmaxf(mx, __shfl_xor(mx, 4));
      mx = fmaxf(mx, __shfl_xor(mx, 8));
      const float mnew = fmaxf(m[r], mx);
      const float corr = __expf(m[r] - mnew);
      float rs = 0.f;
#pragma unroll
      for (int n = 0; n < 4; ++n) { const float p = __expf(s[n][r] - mnew); s[n][r] = p; rs += p; }
      rs += __shfl_xor(rs, 1);
      rs += __shfl_xor(rs, 2);
      rs += __shfl_xor(rs, 4);
      rs += __shfl_xor(rs, 8);
      l[r] = l[r] * corr + rs; m[r] = mnew;
#pragma unroll
      for (int n = 0; n < 4; ++n) oacc[n][r] *= corr;
    }

    // ---- pack P -> per-wave LDS (u32 = hi | lo<<16) ----
#pragma unroll
    for (int r = 0; r < 4; ++r) {
      const int prow = (g << 2) + r;
#pragma unroll
      for (int n = 0; n < 4; ++n) {
        unsigned short hh, ll; split2(s[n][r], hh, ll);
        Pw[wave][prow * 68 + n * 16 + j] = (unsigned int)hh | ((unsigned int)ll << 16);
      }
    }

    // ---- P A-fragments ----
    s16x8 pah[2], pal[2];
#pragma unroll
    for (int c = 0; c < 2; ++c) {
      const int pbase = j * 68 + c * 32 + g * 8;
      unsigned int wv8[8];
      *reinterpret_cast<int4*>(&wv8[0]) = *reinterpret_cast<const int4*>(&Pw[wave][pbase]);
      *reinterpret_cast<int4*>(&wv8[4]) = *reinterpret_cast<const int4*>(&Pw[wave][pbase + 4]);
#pragma unroll
      for (int i = 0; i < 8; ++i) {
        pah[c][i] = (short)(wv8[i] & 0xffffu);
        pal[c][i] = (short)(wv8[i] >> 16);
      }
    }

    // ---- O += P V ----
#pragma unroll
    for (int c = 0; c < 2; ++c) {
      const int koff = c * 32 + g * 8;
#pragma unroll
      for (int n = 0; n < 4; ++n) {
        const int hd = n * 16 + j;
        const int el = hd * 64 + (koff ^ ((hd & 7) << 3));
        const s16x8 vh = *reinterpret_cast<const s16x8*>(&Vsh_hi[el]);
        const s16x8 vl = *reinterpret_cast<const s16x8*>(&Vsh_lo[el]);
        oacc[n] = __builtin_amdgcn_mfma_f32_16x16x32_bf16(pah[c], vh, oacc[n], 0, 0, 0);
        oacc[n] = __builtin_amdgcn_mfma_f32_16x16x32_bf16(pah[c], vl, oacc[n], 0, 0, 0);
        oacc[n] = __builtin_amdgcn_mfma_f32_16x16x32_bf16(pal[c], vh, oacc[n], 0, 0, 0);
      }
    }
  }
#undef LOAD_TILE

  float inv[4];
#pragma unroll
  for (int r = 0; r < 4; ++r) inv[r] = 1.f / l[r];
#pragma unroll
  for (int n = 0; n < 4; ++n) {
    const int hd = n * 16 + j;
#pragma unroll
    for (int r = 0; r < 4; ++r) {
      const int q = q0 + wave * 16 + (g << 2) + r;
      AO[((size_t)b * SEQ + q) * FEAT + h * HD + hd] = oacc[n][r] * inv[r];
    }
  }
}

extern "C" void kernel_launch(void* const* d_in, const int* in_sizes, int n_in,
                              void* d_out, int out_size, void* d_ws, size_t ws_size,
                              hipStream_t stream) {
  const float* x_cur  = (const float*)d_in[0];
  const float* x_past = (const float*)d_in[1];
  const float* wq = (const float*)d_in[2];
  const float* bq = (const float*)d_in[3];
  const float* wk = (const float*)d_in[4];
  const float* bk = (const float*)d_in[5];
  const float* wv = (const float*)d_in[6];
  const float* bv = (const float*)d_in[7];
  const float* wo = (const float*)d_in[8];
  const float* bo = (const float*)d_in[9];
  float* out = (float*)d_out;

  const size_t n = (size_t)NROWS * FEAT;   // 4,194,304
  unsigned short* Qhi  = (unsigned short*)d_ws;
  unsigned short* Qlo  = Qhi + n;
  unsigned short* Khi  = Qhi + 2 * n;
  unsigned short* Klo  = Qhi + 3 * n;
  unsigned short* Vthi = Qhi + 4 * n;
  unsigned short* Vtlo = Qhi + 5 * n;
  float* AO = (float*)(Qhi + 6 * n);

  dim3 block(256);
  dim3 gqkv(NROWS / 128, FEAT / 64, 3);
  qkv_proj<<<gqkv, block, 0, stream>>>(x_cur, x_past, wq, bq, wk, bk, wv, bv,
                                       Qhi, Qlo, Khi, Klo, Vthi, Vtlo);

  dim3 gattn(SEQ / 64, BATCH * NHEADS);
  attn_mfma<<<gattn, block, 0, stream>>>(Qhi, Qlo, Khi, Klo, Vthi, Vtlo, AO);

  dim3 gout(NROWS / 128, FEAT / 64);
  out_proj<<<gout, block, 0, stream>>>(AO, wo, bo, out);
}